// Round 3
// baseline (51.651 us; speedup 1.0000x reference)
//
#include <hip/hip_runtime.h>
#include <hip/hip_fp16.h>
#include <math.h>

// Problem constants (match reference)
#define BB 64
#define HH 224
#define WW 224
#define CC 3

constexpr float FACTOR  = 0.2f;
constexpr float SCALE_K = 1.0f / 255.0f;
constexpr float TWO_PI_F = 6.283185307179586f;
constexpr float CX = (WW - 1) * 0.5f;            // 111.5
constexpr float CY = (HH - 1) * 0.5f;            // 111.5
constexpr int PIX = HH * WW;                     // 50176
constexpr int IMG_ELEMS = PIX * CC;              // 150528

constexpr int TILES_X = WW / 16;                 // 14
constexpr int TILES_Y = HH / 16;                 // 14
constexpr int TILES_PER_IMG = TILES_X * TILES_Y; // 196
constexpr int NXCD = 8;
constexpr int NBLOCKS = BB * TILES_PER_IMG;      // 12544

__device__ __forceinline__ int reflect_idx(int i, int n) {
    int m = i % (2 * n);
    if (m < 0) m += 2 * n;
    return (m >= n) ? (2 * n - 1 - m) : m;
}

// block i -> XCD i%8 (HW round-robin); batch b pinned to XCD b%8 in BOTH
// kernels so kernel B's tmp reads hit the L2 kernel A wrote (8 img x 401KB
// = 3.2MB fp16 < 4MB per-XCD L2).
__device__ __forceinline__ void decode_block(int bid, int tid, int& b, int& x, int& y) {
    int xcd  = bid & (NXCD - 1);
    int slot = bid >> 3;
    int bi   = slot / TILES_PER_IMG;
    int t    = slot - bi * TILES_PER_IMG;
    b = xcd + bi * NXCD;
    int ty = t / TILES_X;
    int tx = t - ty * TILES_X;
    x = tx * 16 + (tid & 15);
    y = ty * 16 + (tid >> 4);
}

__device__ __forceinline__ void load_px(const uint2* __restrict__ base, int idx,
                                        float* o) {
    uint2 v = base[idx];
    o[0] = __half2float(__ushort_as_half((unsigned short)(v.x & 0xffffu)));
    o[1] = __half2float(__ushort_as_half((unsigned short)(v.x >> 16)));
    o[2] = __half2float(__ushort_as_half((unsigned short)(v.y & 0xffffu)));
}

// pass 1: rescale + rotate. fp32 HWC in -> packed fp16 RGBA (8B/px) out.
__global__ __launch_bounds__(256)
void rotate_kernel(const float* __restrict__ image, uint2* __restrict__ tmp,
                   const float* __restrict__ angle_u) {
    int b, x, y;
    decode_block(blockIdx.x, threadIdx.x, b, x, y);

    float theta = (2.0f * angle_u[b] - 1.0f) * FACTOR * TWO_PI_F;
    float c = cosf(theta), s = sinf(theta);

    float rx = (float)x - CX;
    float ry = (float)y - CY;
    float xs = c * rx - s * ry + CX;
    float ys = s * rx + c * ry + CY;

    float x0f = floorf(xs), y0f = floorf(ys);
    float fx = xs - x0f, fy = ys - y0f;
    int x0 = (int)x0f, y0 = (int)y0f;
    int x0r = reflect_idx(x0,     WW);
    int x1r = reflect_idx(x0 + 1, WW);
    int y0r = reflect_idx(y0,     HH);
    int y1r = reflect_idx(y0 + 1, HH);

    const float* img = image + (size_t)b * IMG_ELEMS;
    const float* Ia = img + (y0r * WW + x0r) * CC;
    const float* Ib = img + (y0r * WW + x1r) * CC;
    const float* Ic = img + (y1r * WW + x0r) * CC;
    const float* Id = img + (y1r * WW + x1r) * CC;

    const float omfx = 1.0f - fx;
    const float omfy = 1.0f - fy;

    float o[3];
#pragma unroll
    for (int ch = 0; ch < CC; ++ch) {
        float top = Ia[ch] * omfx + Ib[ch] * fx;
        float bot = Ic[ch] * omfx + Id[ch] * fx;
        o[ch] = (top * omfy + bot * fy) * SCALE_K;
    }

    unsigned u0 = __half_as_ushort(__float2half_rn(o[0]));
    unsigned u1 = __half_as_ushort(__float2half_rn(o[1]));
    unsigned u2 = __half_as_ushort(__float2half_rn(o[2]));
    uint2 v;
    v.x = u0 | (u1 << 16);
    v.y = u2;
    tmp[(size_t)b * PIX + y * WW + x] = v;
}

// pass 2+3 fused: zoom then translate(+flip). Exact: pass-3's 4 taps are at
// integer pixels of pass-2's output; each is computed with pass-2's exact
// formula (bilinear over pass-1 output), then combined with pass-3's exact
// tree. Zoom/translate are axis-separable -> 4 source cols x 4 source rows.
__global__ __launch_bounds__(256)
void zoomshift_kernel(const uint2* __restrict__ tmp, float* __restrict__ out,
                      const float* __restrict__ zoom_u,
                      const float* __restrict__ shift_u,
                      const float* __restrict__ flip_u) {
    int b, x, y;
    decode_block(blockIdx.x, threadIdx.x, b, x, y);

    float zh = 1.0f + (2.0f * zoom_u[2 * b + 0] - 1.0f) * FACTOR;
    float zw = 1.0f + (2.0f * zoom_u[2 * b + 1] - 1.0f) * FACTOR;
    float dy = ((2.0f * shift_u[2 * b + 0] - 1.0f) * FACTOR) * (float)HH;
    float dx = ((2.0f * shift_u[2 * b + 1] - 1.0f) * FACTOR) * (float)WW;
    bool flip = flip_u[b] > 0.5f;

    // pass-3 (translate) coords, flip folded into output x
    int xo = flip ? (WW - 1 - x) : x;
    float xs3 = (float)xo - dx;
    float ys3 = (float)y  - dy;
    float x3f = floorf(xs3), y3f = floorf(ys3);
    float fx3 = xs3 - x3f,   fy3 = ys3 - y3f;
    int x30 = (int)x3f, y30 = (int)y3f;
    int qx[2] = { reflect_idx(x30, WW), reflect_idx(x30 + 1, WW) };
    int qy[2] = { reflect_idx(y30, HH), reflect_idx(y30 + 1, HH) };

    // pass-2 (zoom) coords at those integer pixels (separable)
    int cols[2][2]; float fx2[2];
    int rows[2][2]; float fy2[2];
#pragma unroll
    for (int i = 0; i < 2; ++i) {
        float xs2 = zw * ((float)qx[i] - CX) + CX;
        float xf = floorf(xs2);
        fx2[i] = xs2 - xf;
        int x20 = (int)xf;
        cols[i][0] = reflect_idx(x20,     WW);
        cols[i][1] = reflect_idx(x20 + 1, WW);

        float ys2 = zh * ((float)qy[i] - CY) + CY;
        float yf = floorf(ys2);
        fy2[i] = ys2 - yf;
        int y20 = (int)yf;
        rows[i][0] = reflect_idx(y20,     HH);
        rows[i][1] = reflect_idx(y20 + 1, HH);
    }

    const uint2* img = tmp + (size_t)b * PIX;

    // 16 taps: rows (j,r) x cols (i,c), each one aligned 8B load
    float tv[2][2][2][2][3];   // [j][r][i][c][ch], fully unrolled -> registers
#pragma unroll
    for (int j = 0; j < 2; ++j)
#pragma unroll
        for (int r = 0; r < 2; ++r)
#pragma unroll
            for (int i = 0; i < 2; ++i)
#pragma unroll
                for (int cc = 0; cc < 2; ++cc)
                    load_px(img, rows[j][r] * WW + cols[i][cc], tv[j][r][i][cc]);

    float* o = out + ((size_t)b * PIX + (size_t)y * WW + x) * CC;

#pragma unroll
    for (int ch = 0; ch < CC; ++ch) {
        float I[2][2];
#pragma unroll
        for (int j = 0; j < 2; ++j)
#pragma unroll
            for (int i = 0; i < 2; ++i) {
                float top = tv[j][0][i][0][ch] * (1.0f - fx2[i]) + tv[j][0][i][1][ch] * fx2[i];
                float bot = tv[j][1][i][0][ch] * (1.0f - fx2[i]) + tv[j][1][i][1][ch] * fx2[i];
                I[j][i] = top * (1.0f - fy2[j]) + bot * fy2[j];
            }
        float top = I[0][0] * (1.0f - fx3) + I[0][1] * fx3;
        float bot = I[1][0] * (1.0f - fx3) + I[1][1] * fx3;
        o[ch] = top * (1.0f - fy3) + bot * fy3;
    }
}

extern "C" void kernel_launch(void* const* d_in, const int* in_sizes, int n_in,
                              void* d_out, int out_size, void* d_ws, size_t ws_size,
                              hipStream_t stream) {
    const float* image   = (const float*)d_in[0];
    const float* angle_u = (const float*)d_in[1];
    const float* zoom_u  = (const float*)d_in[2];
    const float* shift_u = (const float*)d_in[3];
    const float* flip_u  = (const float*)d_in[4];
    float* out = (float*)d_out;

    uint2* tmp = (uint2*)d_ws;   // B*H*W packed fp16 RGBA, 25.7 MB

    // pass 1: rescale + rotate   image -> tmp (fp16)
    rotate_kernel<<<NBLOCKS, 256, 0, stream>>>(image, tmp, angle_u);
    // pass 2+3 fused: zoom + translate + flip   tmp -> d_out
    zoomshift_kernel<<<NBLOCKS, 256, 0, stream>>>(tmp, out, zoom_u, shift_u, flip_u);
}

// Round 4
// 38.443 us; speedup vs baseline: 1.3436x; 1.3436x over previous
//
#include <hip/hip_runtime.h>
#include <hip/hip_fp16.h>
#include <math.h>

// Problem constants (match reference)
#define BB 64
#define HH 224
#define WW 224
#define CC 3

constexpr float FACTOR  = 0.2f;
constexpr float SCALE_K = 1.0f / 255.0f;
constexpr float TWO_PI_F = 6.283185307179586f;
constexpr float CX = (WW - 1) * 0.5f;            // 111.5
constexpr float CY = (HH - 1) * 0.5f;            // 111.5
constexpr int PIX = HH * WW;                     // 50176
constexpr int IMG_ELEMS = PIX * CC;              // 150528

constexpr int TILES_X = WW / 16;                 // 14
constexpr int TILES_Y = HH / 16;                 // 14
constexpr int TILES_PER_IMG = TILES_X * TILES_Y; // 196
constexpr int NXCD = 8;
constexpr int NBLOCKS = BB * TILES_PER_IMG;      // 12544

// Valid for i in [-n, 2n-1] — true for every coordinate in this pipeline
// (|offsets| bounded by rot 1.414*111.5, zoom 1.2, shift 0.2*224).
// 2 compare/selects instead of ~10-instr magic-mod.
__device__ __forceinline__ int reflect1(int i, int n) {
    i = (i < 0) ? (-1 - i) : i;
    return (i >= n) ? (2 * n - 1 - i) : i;
}

// block i -> XCD i%8 (HW round-robin); batch b pinned to XCD b%8 in BOTH
// kernels so zoomshift's tmp reads hit the L2 rotate wrote (8 img x 401KB
// = 3.2MB fp16 < 4MB per-XCD L2).
__device__ __forceinline__ void decode_tile(int bid, int& b, int& tx, int& ty) {
    int xcd  = bid & (NXCD - 1);
    int slot = bid >> 3;
    int bi   = slot / TILES_PER_IMG;
    int t    = slot - bi * TILES_PER_IMG;
    b = xcd + bi * NXCD;
    ty = t / TILES_X;
    tx = t - ty * TILES_X;
}

__device__ __forceinline__ void unpack_px(uint2 v, float* o) {
    o[0] = __half2float(__ushort_as_half((unsigned short)(v.x & 0xffffu)));
    o[1] = __half2float(__ushort_as_half((unsigned short)(v.x >> 16)));
    o[2] = __half2float(__ushort_as_half((unsigned short)(v.y & 0xffffu)));
}

// pass 1: rescale + rotate. fp32 HWC in -> packed fp16 RGBA (8B/px) out.
__global__ __launch_bounds__(256)
void rotate_kernel(const float* __restrict__ image, uint2* __restrict__ tmp,
                   const float* __restrict__ angle_u) {
    int b, tx, ty;
    decode_tile(blockIdx.x, b, tx, ty);
    const int x = tx * 16 + (threadIdx.x & 15);
    const int y = ty * 16 + (threadIdx.x >> 4);

    float theta = (2.0f * angle_u[b] - 1.0f) * FACTOR * TWO_PI_F;
    float c = cosf(theta), s = sinf(theta);

    float rx = (float)x - CX;
    float ry = (float)y - CY;
    float xs = c * rx - s * ry + CX;
    float ys = s * rx + c * ry + CY;

    float x0f = floorf(xs), y0f = floorf(ys);
    float fx = xs - x0f, fy = ys - y0f;
    int x0 = (int)x0f, y0 = (int)y0f;
    int x0r = reflect1(x0,     WW);
    int x1r = reflect1(x0 + 1, WW);
    int y0r = reflect1(y0,     HH);
    int y1r = reflect1(y0 + 1, HH);

    const float* img = image + (size_t)b * IMG_ELEMS;
    const float* Ia = img + (y0r * WW + x0r) * CC;
    const float* Ib = img + (y0r * WW + x1r) * CC;
    const float* Ic = img + (y1r * WW + x0r) * CC;
    const float* Id = img + (y1r * WW + x1r) * CC;

    const float omfx = 1.0f - fx;
    const float omfy = 1.0f - fy;

    float o[3];
#pragma unroll
    for (int ch = 0; ch < CC; ++ch) {
        float top = Ia[ch] * omfx + Ib[ch] * fx;
        float bot = Ic[ch] * omfx + Id[ch] * fx;
        o[ch] = (top * omfy + bot * fy) * SCALE_K;
    }

    unsigned u0 = __half_as_ushort(__float2half_rn(o[0]));
    unsigned u1 = __half_as_ushort(__float2half_rn(o[1]));
    unsigned u2 = __half_as_ushort(__float2half_rn(o[2]));
    uint2 v;
    v.x = u0 | (u1 << 16);
    v.y = u2;
    tmp[(size_t)b * PIX + y * WW + x] = v;
}

// pass 2+3 fused via cooperative LDS staging.
// Key facts: floor(y - dy) = y + floor(-dy) for integer y, so the translate
// stage's fractional weights (fx3, fy3) are batch-uniform and its integer
// source coords for a 16x16 output tile span a CONTIGUOUS 17x17 window.
// Block stages Z[17][17] = zoom-stage values (each = 4 fp16 gathers, exact
// reference FP tree) into LDS; each thread then blends 4 Z entries.
// 1156 gathers/tile instead of 4096.
__global__ __launch_bounds__(256)
void zoomshift_kernel(const uint2* __restrict__ tmp, float* __restrict__ out,
                      const float* __restrict__ zoom_u,
                      const float* __restrict__ shift_u,
                      const float* __restrict__ flip_u) {
    int b, tx, ty;
    decode_tile(blockIdx.x, b, tx, ty);

    const float zh = 1.0f + (2.0f * zoom_u[2 * b + 0] - 1.0f) * FACTOR;
    const float zw = 1.0f + (2.0f * zoom_u[2 * b + 1] - 1.0f) * FACTOR;
    const float dy = ((2.0f * shift_u[2 * b + 0] - 1.0f) * FACTOR) * (float)HH;
    const float dx = ((2.0f * shift_u[2 * b + 1] - 1.0f) * FACTOR) * (float)WW;
    const bool flip = flip_u[b] > 0.5f;

    const float ndxf = floorf(-dx), ndyf = floorf(-dy);
    const int Kx = (int)ndxf, Ky = (int)ndyf;
    const float fx3 = -dx - ndxf;          // batch-uniform translate weights
    const float fy3 = -dy - ndyf;

    // raw (pre-reflect) window origin of the 17x17 Z tile
    const int Xmin = (flip ? (WW - 16 - tx * 16) : tx * 16) + Kx;
    const int Ymin = ty * 16 + Ky;

    __shared__ float Z[17 * 17 * 3];

    const uint2* img = tmp + (size_t)b * PIX;

    for (int e = threadIdx.x; e < 17 * 17; e += 256) {
        int ey = e / 17;
        int ex = e - ey * 17;
        int Yr = reflect1(Ymin + ey, HH);
        int Xr = reflect1(Xmin + ex, WW);

        float ys2 = zh * ((float)Yr - CY) + CY;   // exact reference zoom expr
        float xs2 = zw * ((float)Xr - CX) + CX;
        float yf = floorf(ys2), xf = floorf(xs2);
        float fy2 = ys2 - yf, fx2 = xs2 - xf;
        int y20 = (int)yf, x20 = (int)xf;
        int r0 = reflect1(y20,     HH);
        int r1 = reflect1(y20 + 1, HH);
        int c0 = reflect1(x20,     WW);
        int c1 = reflect1(x20 + 1, WW);

        uint2 va = img[r0 * WW + c0];
        uint2 vb = img[r0 * WW + c1];
        uint2 vc = img[r1 * WW + c0];
        uint2 vd = img[r1 * WW + c1];
        float A[3], Bv[3], Cv[3], Dv[3];
        unpack_px(va, A); unpack_px(vb, Bv); unpack_px(vc, Cv); unpack_px(vd, Dv);

        const float omfx = 1.0f - fx2, omfy = 1.0f - fy2;
        float* zp = &Z[e * 3];
#pragma unroll
        for (int ch = 0; ch < CC; ++ch) {
            float top = A[ch]  * omfx + Bv[ch] * fx2;
            float bot = Cv[ch] * omfx + Dv[ch] * fx2;
            zp[ch] = top * omfy + bot * fy2;
        }
    }
    __syncthreads();

    const int lx = threadIdx.x & 15, ly = threadIdx.x >> 4;
    const int x = tx * 16 + lx, y = ty * 16 + ly;
    const int ix = flip ? (15 - lx) : lx;     // position within the raw window
    const int iy = ly;

    const float* z00 = &Z[(iy * 17 + ix) * 3];
    const float* z01 = &Z[(iy * 17 + ix + 1) * 3];
    const float* z10 = &Z[((iy + 1) * 17 + ix) * 3];
    const float* z11 = &Z[((iy + 1) * 17 + ix + 1) * 3];

    float* o = out + ((size_t)b * PIX + (size_t)y * WW + x) * CC;
    const float omfx3 = 1.0f - fx3, omfy3 = 1.0f - fy3;
#pragma unroll
    for (int ch = 0; ch < CC; ++ch) {
        float top = z00[ch] * omfx3 + z01[ch] * fx3;
        float bot = z10[ch] * omfx3 + z11[ch] * fx3;
        o[ch] = top * omfy3 + bot * fy3;
    }
}

extern "C" void kernel_launch(void* const* d_in, const int* in_sizes, int n_in,
                              void* d_out, int out_size, void* d_ws, size_t ws_size,
                              hipStream_t stream) {
    const float* image   = (const float*)d_in[0];
    const float* angle_u = (const float*)d_in[1];
    const float* zoom_u  = (const float*)d_in[2];
    const float* shift_u = (const float*)d_in[3];
    const float* flip_u  = (const float*)d_in[4];
    float* out = (float*)d_out;

    uint2* tmp = (uint2*)d_ws;   // B*H*W packed fp16 RGBA, 25.7 MB

    // pass 1: rescale + rotate   image -> tmp (fp16)
    rotate_kernel<<<NBLOCKS, 256, 0, stream>>>(image, tmp, angle_u);
    // pass 2+3 fused: zoom + translate + flip   tmp -> d_out
    zoomshift_kernel<<<NBLOCKS, 256, 0, stream>>>(tmp, out, zoom_u, shift_u, flip_u);
}

// Round 5
// 37.880 us; speedup vs baseline: 1.3635x; 1.0149x over previous
//
#include <hip/hip_runtime.h>
#include <hip/hip_fp16.h>
#include <math.h>

// Problem constants (match reference)
#define BB 64
#define HH 224
#define WW 224
#define CC 3

constexpr float FACTOR  = 0.2f;
constexpr float SCALE_K = 1.0f / 255.0f;
constexpr float TWO_PI_F = 6.283185307179586f;
constexpr float CX = (WW - 1) * 0.5f;            // 111.5
constexpr float CY = (HH - 1) * 0.5f;            // 111.5
constexpr int PIX = HH * WW;                     // 50176
constexpr int IMG_ELEMS = PIX * CC;              // 150528

constexpr int TILES_X = WW / 16;                 // 14
constexpr int TILES_Y = HH / 16;                 // 14
constexpr int TILES_PER_IMG = TILES_X * TILES_Y; // 196
constexpr int NXCD = 8;
constexpr int NBLOCKS = BB * TILES_PER_IMG;      // 12544

// Under-aligned vector loads: HW supports dword-aligned dwordx4/x2.
typedef float f32x4 __attribute__((ext_vector_type(4), aligned(4)));
typedef float f32x2 __attribute__((ext_vector_type(2), aligned(4)));
typedef unsigned int u32x4 __attribute__((ext_vector_type(4), aligned(8)));

// Valid for i in [-n, 2n-1] — true for every coordinate in this pipeline.
__device__ __forceinline__ int reflect1(int i, int n) {
    i = (i < 0) ? (-1 - i) : i;
    return (i >= n) ? (2 * n - 1 - i) : i;
}

// block i -> XCD i%8 (HW round-robin); batch b pinned to XCD b%8 in BOTH
// kernels so zoomshift's tmp reads hit the L2 rotate wrote (8 img x 401KB
// = 3.2MB fp16 < 4MB per-XCD L2). 12544 % 8 == 0 -> bijective.
__device__ __forceinline__ void decode_tile(int bid, int& b, int& tx, int& ty) {
    int xcd  = bid & (NXCD - 1);
    int slot = bid >> 3;
    int bi   = slot / TILES_PER_IMG;
    int t    = slot - bi * TILES_PER_IMG;
    b = xcd + bi * NXCD;
    ty = t / TILES_X;
    tx = t - ty * TILES_X;
}

__device__ __forceinline__ float h2f(unsigned short u) {
    return __half2float(__ushort_as_half(u));
}

// pass 1: rescale + rotate. fp32 HWC in -> packed fp16 RGBA (8B/px) out.
// The two x-taps of a bilinear row are adjacent pixels (or the same pixel at
// a reflect fold), so each row's 2 taps = 6 consecutive floats: one dwordx4
// + one dwordx2, with a branchless sel covering {x1r-x0r} in {+1, 0, -1}.
// Base clamped to WW-2 so the 6-float window never leaves the image row
// range (last float touched: ((223*224+222)*3)+5 = IMG_ELEMS-1).
__global__ __launch_bounds__(256)
void rotate_kernel(const float* __restrict__ image, uint2* __restrict__ tmp,
                   const float* __restrict__ angle_u) {
    int b, tx, ty;
    decode_tile(blockIdx.x, b, tx, ty);
    const int x = tx * 16 + (threadIdx.x & 15);
    const int y = ty * 16 + (threadIdx.x >> 4);

    float theta = (2.0f * angle_u[b] - 1.0f) * FACTOR * TWO_PI_F;
    float c = __cosf(theta), s = __sinf(theta);

    float rx = (float)x - CX;
    float ry = (float)y - CY;
    float xs = c * rx - s * ry + CX;
    float ys = s * rx + c * ry + CY;

    float x0f = floorf(xs), y0f = floorf(ys);
    float fx = xs - x0f, fy = ys - y0f;
    int x0 = (int)x0f, y0 = (int)y0f;
    int x0r = reflect1(x0,     WW);
    int x1r = reflect1(x0 + 1, WW);
    int y0r = reflect1(y0,     HH);
    int y1r = reflect1(y0 + 1, HH);

    int xl = min(x0r, x1r); xl = min(xl, WW - 2);
    const bool sA = (x0r != xl);           // A = floats [3..5] else [0..2]
    const bool sB = (x1r != xl);

    const float* img = image + (size_t)b * IMG_ELEMS;
    const float* rT = img + (y0r * WW + xl) * CC;
    const float* rB = img + (y1r * WW + xl) * CC;

    f32x4 t4 = *(const f32x4*)rT;
    f32x2 t2 = *(const f32x2*)(rT + 4);
    f32x4 b4 = *(const f32x4*)rB;
    f32x2 b2 = *(const f32x2*)(rB + 4);

    float TA[3] = { sA ? t4.w : t4.x, sA ? t2.x : t4.y, sA ? t2.y : t4.z };
    float TB[3] = { sB ? t4.w : t4.x, sB ? t2.x : t4.y, sB ? t2.y : t4.z };
    float BA[3] = { sA ? b4.w : b4.x, sA ? b2.x : b4.y, sA ? b2.y : b4.z };
    float BC[3] = { sB ? b4.w : b4.x, sB ? b2.x : b4.y, sB ? b2.y : b4.z };

    const float omfx = 1.0f - fx;
    const float omfy = 1.0f - fy;

    float o[3];
#pragma unroll
    for (int ch = 0; ch < CC; ++ch) {
        float top = TA[ch] * omfx + TB[ch] * fx;
        float bot = BA[ch] * omfx + BC[ch] * fx;
        o[ch] = (top * omfy + bot * fy) * SCALE_K;
    }

    unsigned u0 = __half_as_ushort(__float2half_rn(o[0]));
    unsigned u1 = __half_as_ushort(__float2half_rn(o[1]));
    unsigned u2 = __half_as_ushort(__float2half_rn(o[2]));
    uint2 v;
    v.x = u0 | (u1 << 16);
    v.y = u2;
    tmp[(size_t)b * PIX + y * WW + x] = v;
}

// pass 2+3 fused via cooperative LDS staging (see R4 derivation). Each Z
// entry's 4 taps = 2 row-pairs; a row-pair (2 adjacent fp16 pixels) is one
// 16B load with branchless sel for the reflect-fold cases.
__global__ __launch_bounds__(256)
void zoomshift_kernel(const uint2* __restrict__ tmp, float* __restrict__ out,
                      const float* __restrict__ zoom_u,
                      const float* __restrict__ shift_u,
                      const float* __restrict__ flip_u) {
    int b, tx, ty;
    decode_tile(blockIdx.x, b, tx, ty);

    const float zh = 1.0f + (2.0f * zoom_u[2 * b + 0] - 1.0f) * FACTOR;
    const float zw = 1.0f + (2.0f * zoom_u[2 * b + 1] - 1.0f) * FACTOR;
    const float dy = ((2.0f * shift_u[2 * b + 0] - 1.0f) * FACTOR) * (float)HH;
    const float dx = ((2.0f * shift_u[2 * b + 1] - 1.0f) * FACTOR) * (float)WW;
    const bool flip = flip_u[b] > 0.5f;

    const float ndxf = floorf(-dx), ndyf = floorf(-dy);
    const int Kx = (int)ndxf, Ky = (int)ndyf;
    const float fx3 = -dx - ndxf;          // batch-uniform translate weights
    const float fy3 = -dy - ndyf;

    // raw (pre-reflect) window origin of the 17x17 Z tile
    const int Xmin = (flip ? (WW - 16 - tx * 16) : tx * 16) + Kx;
    const int Ymin = ty * 16 + Ky;

    __shared__ float Z[17 * 17 * 3];

    const uint2* img = tmp + (size_t)b * PIX;

    for (int e = threadIdx.x; e < 17 * 17; e += 256) {
        int ey = e / 17;
        int ex = e - ey * 17;
        int Yr = reflect1(Ymin + ey, HH);
        int Xr = reflect1(Xmin + ex, WW);

        float ys2 = zh * ((float)Yr - CY) + CY;   // exact reference zoom expr
        float xs2 = zw * ((float)Xr - CX) + CX;
        float yf = floorf(ys2), xf = floorf(xs2);
        float fy2 = ys2 - yf, fx2 = xs2 - xf;
        int y20 = (int)yf, x20 = (int)xf;
        int r0 = reflect1(y20,     HH);
        int r1 = reflect1(y20 + 1, HH);
        int c0 = reflect1(x20,     WW);
        int c1 = reflect1(x20 + 1, WW);

        int cl = min(c0, c1); cl = min(cl, WW - 2);
        const bool sA = (c0 != cl);        // pixel = words {z,w} else {x,y}
        const bool sB = (c1 != cl);

        u32x4 vT = *(const u32x4*)(img + r0 * WW + cl);
        u32x4 vB = *(const u32x4*)(img + r1 * WW + cl);

        unsigned aT0 = sA ? vT.z : vT.x, aT1 = sA ? vT.w : vT.y;
        unsigned bT0 = sB ? vT.z : vT.x, bT1 = sB ? vT.w : vT.y;
        unsigned aB0 = sA ? vB.z : vB.x, aB1 = sA ? vB.w : vB.y;
        unsigned bB0 = sB ? vB.z : vB.x, bB1 = sB ? vB.w : vB.y;

        float A[3] = { h2f((unsigned short)(aT0 & 0xffffu)),
                       h2f((unsigned short)(aT0 >> 16)),
                       h2f((unsigned short)(aT1 & 0xffffu)) };
        float Bv[3] = { h2f((unsigned short)(bT0 & 0xffffu)),
                        h2f((unsigned short)(bT0 >> 16)),
                        h2f((unsigned short)(bT1 & 0xffffu)) };
        float Cv[3] = { h2f((unsigned short)(aB0 & 0xffffu)),
                        h2f((unsigned short)(aB0 >> 16)),
                        h2f((unsigned short)(aB1 & 0xffffu)) };
        float Dv[3] = { h2f((unsigned short)(bB0 & 0xffffu)),
                        h2f((unsigned short)(bB0 >> 16)),
                        h2f((unsigned short)(bB1 & 0xffffu)) };

        const float omfx = 1.0f - fx2, omfy = 1.0f - fy2;
        float* zp = &Z[e * 3];
#pragma unroll
        for (int ch = 0; ch < CC; ++ch) {
            float top = A[ch]  * omfx + Bv[ch] * fx2;
            float bot = Cv[ch] * omfx + Dv[ch] * fx2;
            zp[ch] = top * omfy + bot * fy2;
        }
    }
    __syncthreads();

    const int lx = threadIdx.x & 15, ly = threadIdx.x >> 4;
    const int x = tx * 16 + lx, y = ty * 16 + ly;
    const int ix = flip ? (15 - lx) : lx;     // position within the raw window
    const int iy = ly;

    const float* z00 = &Z[(iy * 17 + ix) * 3];
    const float* z01 = &Z[(iy * 17 + ix + 1) * 3];
    const float* z10 = &Z[((iy + 1) * 17 + ix) * 3];
    const float* z11 = &Z[((iy + 1) * 17 + ix + 1) * 3];

    float* o = out + ((size_t)b * PIX + (size_t)y * WW + x) * CC;
    const float omfx3 = 1.0f - fx3, omfy3 = 1.0f - fy3;
#pragma unroll
    for (int ch = 0; ch < CC; ++ch) {
        float top = z00[ch] * omfx3 + z01[ch] * fx3;
        float bot = z10[ch] * omfx3 + z11[ch] * fx3;
        o[ch] = top * omfy3 + bot * fy3;
    }
}

extern "C" void kernel_launch(void* const* d_in, const int* in_sizes, int n_in,
                              void* d_out, int out_size, void* d_ws, size_t ws_size,
                              hipStream_t stream) {
    const float* image   = (const float*)d_in[0];
    const float* angle_u = (const float*)d_in[1];
    const float* zoom_u  = (const float*)d_in[2];
    const float* shift_u = (const float*)d_in[3];
    const float* flip_u  = (const float*)d_in[4];
    float* out = (float*)d_out;

    uint2* tmp = (uint2*)d_ws;   // B*H*W packed fp16 RGBA, 25.7 MB

    // pass 1: rescale + rotate   image -> tmp (fp16)
    rotate_kernel<<<NBLOCKS, 256, 0, stream>>>(image, tmp, angle_u);
    // pass 2+3 fused: zoom + translate + flip   tmp -> d_out
    zoomshift_kernel<<<NBLOCKS, 256, 0, stream>>>(tmp, out, zoom_u, shift_u, flip_u);
}